// Round 1
// baseline (256.657 us; speedup 1.0000x reference)
//
#include <hip/hip_runtime.h>
#include <math.h>
#include <stdint.h>

#define Bn 8
#define Nn 2048
#define Cn 128

typedef _Float16 f16x8 __attribute__((ext_vector_type(8)));
typedef float    f32x4 __attribute__((ext_vector_type(4)));

// ---------------------------------------------------------------------------
// Kernel 1: v[c] = sum_d W_w[d][c] * a_w[C+d] ;  b2 = sum_c W_b[c]*a_w[C+c]
// (si / a_b cancel in the row normalization and are never computed)
// ---------------------------------------------------------------------------
__global__ void prep_kernel(const float* __restrict__ Ww, const float* __restrict__ Wb,
                            const float* __restrict__ aw, float* __restrict__ vout) {
    int c = threadIdx.x;                         // 128 threads
    float acc = 0.f;
    for (int d = 0; d < Cn; ++d) acc += Ww[d * Cn + c] * aw[Cn + d];
    vout[c] = acc;
    if (c == 0) {
        float b2 = 0.f;
        for (int i = 0; i < Cn; ++i) b2 += Wb[i] * aw[Cn + i];
        vout[Cn] = b2;
    }
}

// ---------------------------------------------------------------------------
// Kernel 2: per 64-row chunk of h:
//   wexp[b,n] = exp(h[b,n,:]·v + b2)
//   hT[b][c][n] = (f16) h[b][n][c]   (transpose so MFMA B-frags are 16B rows)
// grid = B * N/64 = 256 blocks, 256 threads
// ---------------------------------------------------------------------------
__global__ __launch_bounds__(256) void rows_kernel(const float* __restrict__ h,
                                                   const float* __restrict__ vb2,
                                                   float* __restrict__ wexp,
                                                   _Float16* __restrict__ hT) {
    __shared__ float tile[64][133];              // +5 pad: 2-way-max LDS conflicts
    int bid = blockIdx.x;
    int b   = bid >> 5;
    int n0  = (bid & 31) << 6;
    const float* hblk = h + ((size_t)(b * Nn + n0)) * Cn;
    int tid = threadIdx.x;

    // load 64 rows x 128 cols, coalesced float4
    {
        int r = tid >> 2, qq = tid & 3;
        const float4* rowp = (const float4*)(hblk + (size_t)r * Cn);
#pragma unroll
        for (int i = 0; i < 8; ++i) {
            int f4 = i * 4 + qq;                 // float4 index within row
            float4 x = rowp[f4];
            int cb = f4 * 4;
            tile[r][cb + 0] = x.x; tile[r][cb + 1] = x.y;
            tile[r][cb + 2] = x.z; tile[r][cb + 3] = x.w;
        }
    }
    __syncthreads();

    if (tid < 64) {                              // one thread per row: dot + exp
        float acc = 0.f;
        for (int i = 0; i < Cn; ++i) acc += tile[tid][i] * vb2[i];
        wexp[b * Nn + n0 + tid] = expf(acc + vb2[Cn]);
    }

    // transposed f16 write: lane along n (contiguous 128B stores)
    int lane = tid & 63, cg = tid >> 6;
    for (int c = cg; c < Cn; c += 4) {
        hT[((size_t)(b * Cn + c)) * Nn + n0 + lane] = (_Float16)tile[lane][c];
    }
}

// ---------------------------------------------------------------------------
// Kernel 3: out[b,i,:] = (1/den_i) * sum_j (A[b,i,j]*w_j) * h[b,j,:]
// grid = B * N/64 = 256 blocks (1/CU), 512 threads = 8 waves:
//   wave w: row-tile rw = w&3 (16 rows), K-half k2 = w>>2
// MFMA 16x16x32 f16: A-frag = P[m][k] (m=lane&15, k=quad*8+i),
//                    B-frag = hT[c][k] (c=lane&15 of tile), D: col=lane&15,row=quad*4+reg
// ---------------------------------------------------------------------------
__global__ __launch_bounds__(512) void attn_kernel(const float* __restrict__ A,
                                                   const float* __restrict__ wexp,
                                                   const _Float16* __restrict__ hT,
                                                   float* __restrict__ out) {
    __shared__ float red[64 * 132];              // K-split partial accumulators
    __shared__ float dred[64];                   // K-split partial denominators

    int bid = blockIdx.x;
    int b   = bid >> 5;
    int i0  = (bid & 31) << 6;
    int tid = threadIdx.x;
    int w = tid >> 6, l = tid & 63;
    int rw = w & 3, k2 = w >> 2;
    int m = l & 15, q = l >> 4;
    int row_l = rw * 16 + m;                     // local row handled by this lane's A-frag

    const float*    Arow = A    + ((size_t)(b * Nn + i0 + row_l)) * Nn;
    const float*    wb   = wexp + (size_t)b * Nn;
    const _Float16* hTb  = hT   + (size_t)b * Cn * Nn;

    f32x4 acc[8];
#pragma unroll
    for (int t = 0; t < 8; ++t) acc[t] = (f32x4){0.f, 0.f, 0.f, 0.f};
    float dsum = 0.f;

    for (int t = 0; t < 32; ++t) {
        int j = k2 * 32 + t * 64 + q * 8;        // this lane's 8 contiguous k's
        float4 a0 = *(const float4*)(Arow + j);
        float4 a1 = *(const float4*)(Arow + j + 4);
        float4 w0 = *(const float4*)(wb + j);
        float4 w1 = *(const float4*)(wb + j + 4);
        float p0 = a0.x * w0.x, p1 = a0.y * w0.y, p2 = a0.z * w0.z, p3 = a0.w * w0.w;
        float p4 = a1.x * w1.x, p5 = a1.y * w1.y, p6 = a1.z * w1.z, p7 = a1.w * w1.w;
        dsum += ((p0 + p1) + (p2 + p3)) + ((p4 + p5) + (p6 + p7));   // exact-f32 denom
        f16x8 af;
        af[0] = (_Float16)p0; af[1] = (_Float16)p1; af[2] = (_Float16)p2; af[3] = (_Float16)p3;
        af[4] = (_Float16)p4; af[5] = (_Float16)p5; af[6] = (_Float16)p6; af[7] = (_Float16)p7;
        const _Float16* hcol = hTb + j;
#pragma unroll
        for (int tt = 0; tt < 8; ++tt) {         // 8 c-tiles of 16 → full C=128
            f16x8 bf = *(const f16x8*)(hcol + (size_t)(tt * 16 + m) * Nn);
            acc[tt] = __builtin_amdgcn_mfma_f32_16x16x32_f16(af, bf, acc[tt], 0, 0, 0);
        }
    }

    // reduce denom across quads (lanes with same m)
    dsum += __shfl_xor(dsum, 16, 64);
    dsum += __shfl_xor(dsum, 32, 64);

    if (k2 == 1) {                               // K-half 1 dumps partials to LDS
        if (l < 16) dred[row_l] = dsum;
#pragma unroll
        for (int tt = 0; tt < 8; ++tt)
#pragma unroll
            for (int r = 0; r < 4; ++r)
                red[(rw * 16 + q * 4 + r) * 132 + tt * 16 + m] = acc[tt][r];
    }
    __syncthreads();
    if (k2 == 0) {                               // K-half 0 combines + normalizes + stores
        float dtot = dsum + dred[row_l];
        float invd = 1.f / dtot;                 // valid per lane for row m, all quads
        float* ob = out + ((size_t)(b * Nn + i0)) * Cn;
#pragma unroll
        for (int r = 0; r < 4; ++r) {
            int rloc = q * 4 + r;                // C/D-layout row for this reg
            float iv = __shfl(invd, rloc, 64);   // invd for row rw*16+rloc lives on lane rloc
#pragma unroll
            for (int tt = 0; tt < 8; ++tt) {
                float v = (acc[tt][r] + red[(rw * 16 + rloc) * 132 + tt * 16 + m]) * iv;
                ob[(size_t)(rw * 16 + rloc) * Cn + tt * 16 + m] = v;
            }
        }
    }
}

// ---------------------------------------------------------------------------
extern "C" void kernel_launch(void* const* d_in, const int* in_sizes, int n_in,
                              void* d_out, int out_size, void* d_ws, size_t ws_size,
                              hipStream_t stream) {
    const float* h  = (const float*)d_in[0];
    const float* A  = (const float*)d_in[1];
    const float* Ww = (const float*)d_in[2];
    const float* Wb = (const float*)d_in[3];
    const float* aw = (const float*)d_in[4];
    // d_in[5] = a_b : cancels in the row normalization, unused
    float* out = (float*)d_out;

    char* ws = (char*)d_ws;
    _Float16* hT   = (_Float16*)ws;                                    // 8*128*2048 f16 = 4 MB
    float*    wexp = (float*)(ws + (size_t)Bn * Cn * Nn * 2);          // 8*2048 f32 = 64 KB
    float*    vout = (float*)(ws + (size_t)Bn * Cn * Nn * 2 + (size_t)Bn * Nn * 4); // 129 f32

    prep_kernel<<<1, 128, 0, stream>>>(Ww, Wb, aw, vout);
    rows_kernel<<<Bn * (Nn / 64), 256, 0, stream>>>(h, vout, wexp, hT);
    attn_kernel<<<Bn * (Nn / 64), 512, 0, stream>>>(A, wexp, hT, out);
}

// Round 2
// 234.900 us; speedup vs baseline: 1.0926x; 1.0926x over previous
//
#include <hip/hip_runtime.h>
#include <math.h>
#include <stdint.h>

#define Bn 8
#define Nn 2048
#define Cn 128
#define NKB (Nn / 32)   // 64 K-blocks of 32 columns each

typedef _Float16 f16x8 __attribute__((ext_vector_type(8)));
typedef float    f32x4 __attribute__((ext_vector_type(4)));

// ---------------------------------------------------------------------------
// rows_kernel: fused prep + row transform. Per 64-row chunk of h:
//   v[c] = sum_d Ww[d][c]*aw[C+d]; b2 = Wb·aw2   (recomputed per block, L3-hot)
//   wexp[b,n] = exp(h[b,n,:]·v + b2)
//   hTt[b][kb][c][ks] = (f16) h[b][kb*32+ks][c]  (K-blocked tile layout so the
//       attn kernel's B-frag loads are 1 KB contiguous — no 4 KB-stride gather)
// grid = 256 blocks (b = bid&7 for XCD-local L2 residency), 256 threads
// ---------------------------------------------------------------------------
__global__ __launch_bounds__(256) void rows_kernel(const float* __restrict__ h,
                                                   const float* __restrict__ Ww,
                                                   const float* __restrict__ Wb,
                                                   const float* __restrict__ aw,
                                                   float* __restrict__ wexp,
                                                   _Float16* __restrict__ hTt) {
    __shared__ float tile[64][132];      // 132: float4-aligned rows, modest conflicts
    __shared__ float vsh[128];           // half-0 partial of v
    __shared__ float vpart[128];         // half-1 partial of v
    __shared__ float b2sh;

    int bid = blockIdx.x;
    int b   = bid & 7;                   // XCD-aligned batch
    int n0  = (bid >> 3) << 6;           // 32 row-chunks of 64
    int tid = threadIdx.x;

    // v partials: threads 0..127 do d in [0,64), 128..255 do d in [64,128)
    {
        int c = tid & 127, half = tid >> 7;
        float acc = 0.f;
#pragma unroll
        for (int dd = 0; dd < 64; ++dd) {
            int d = half * 64 + dd;
            acc += Ww[d * Cn + c] * aw[Cn + d];
        }
        if (half) vpart[c] = acc; else vsh[c] = acc;
    }
    // b2 = Wb·aw2 by wave 0
    if (tid < 64) {
        float b2p = Wb[tid] * aw[Cn + tid] + Wb[tid + 64] * aw[Cn + tid + 64];
        b2p += __shfl_xor(b2p, 32, 64);
        b2p += __shfl_xor(b2p, 16, 64);
        b2p += __shfl_xor(b2p, 8, 64);
        b2p += __shfl_xor(b2p, 4, 64);
        b2p += __shfl_xor(b2p, 2, 64);
        b2p += __shfl_xor(b2p, 1, 64);
        if (tid == 0) b2sh = b2p;
    }
    // stage 64x128 h tile, coalesced float4
    {
        int r = tid >> 2, qq = tid & 3;
        const float4* rowp = (const float4*)(h + (size_t)(b * Nn + n0 + r) * Cn);
#pragma unroll
        for (int i = 0; i < 8; ++i) {
            int f4 = i * 4 + qq;
            float4 x = rowp[f4];
            *(float4*)&tile[r][f4 * 4] = x;
        }
    }
    __syncthreads();

    // dot h·v + exp: 4 threads per row, 32 elems each, shfl-combine
    {
        int r = tid >> 2, pp = tid & 3;
        float acc = 0.f;
#pragma unroll
        for (int ii = 0; ii < 32; ++ii) {
            int i = pp * 32 + ii;
            acc += tile[r][i] * (vsh[i] + vpart[i]);
        }
        acc += __shfl_xor(acc, 1, 64);
        acc += __shfl_xor(acc, 2, 64);
        if (pp == 0) wexp[b * Nn + n0 + r] = expf(acc + b2sh);
    }

    // K-blocked transposed f16 write: hTt[(b*NKB+kb)*Cn*32 + c*32 + ks]
    {
        int l = tid & 63, cg = tid >> 6;
        int kb = (n0 >> 5) + (l >> 5);
        int ks = l & 31;
        _Float16* base = hTt + ((size_t)(b * NKB + kb) * Cn) * 32 + ks;
#pragma unroll
        for (int c = cg; c < Cn; c += 4)
            base[c * 32] = (_Float16)tile[l][c];
    }
}

// ---------------------------------------------------------------------------
// attn_kernel: out[b,i,:] = (1/den_i) * sum_j (A[b,i,j]*w_j) * h[b,j,:]
// grid = 512 blocks (2/CU) x 512 threads (8 waves): 32 rows/block,
// waves = 2 row-tiles x 4-way K-split (interleaved at 32-k granularity).
// B-frags come from hTt tiles: each f16x8 wave-load is 1 KB contiguous.
// ---------------------------------------------------------------------------
__global__ __launch_bounds__(512, 4) void attn_kernel(const float* __restrict__ A,
                                                      const float* __restrict__ wexp,
                                                      const _Float16* __restrict__ hTt,
                                                      float* __restrict__ out) {
    __shared__ float red[3][32][132];    // K-split partial accumulators (waves kw=1..3)
    __shared__ float dred[3][32];        // K-split partial denominators

    int bid = blockIdx.x;
    int b   = bid & 7;                   // XCD-aligned batch (matches rows_kernel)
    int i0  = (bid >> 3) << 5;           // 64 row-tiles of 32
    int tid = threadIdx.x;
    int w = tid >> 6, l = tid & 63;
    int rw = w & 1, kw = w >> 1;
    int m = l & 15, q = l >> 4;
    int row_l = rw * 16 + m;

    const float*    Arow = A    + (size_t)(b * Nn + i0 + row_l) * Nn;
    const float*    wb   = wexp + (size_t)b * Nn;
    const _Float16* hb   = hTt  + (size_t)b * NKB * Cn * 32;

    f32x4 acc[8];
#pragma unroll
    for (int t = 0; t < 8; ++t) acc[t] = (f32x4){0.f, 0.f, 0.f, 0.f};
    float dsum = 0.f;

    for (int t = 0; t < 16; ++t) {
        int kb = kw + t * 4;             // this wave's 32-k block
        int j  = kb * 32 + q * 8;        // lane's 8 consecutive k's
        // issue all independent loads up front (12 x 1 KB in flight)
        const _Float16* hk = hb + (size_t)kb * (Cn * 32) + q * 8;
        f16x8 bfv[8];
#pragma unroll
        for (int tt = 0; tt < 8; ++tt)
            bfv[tt] = *(const f16x8*)(hk + (tt * 16 + m) * 32);
        float4 a0 = *(const float4*)(Arow + j);
        float4 a1 = *(const float4*)(Arow + j + 4);
        float4 w0 = *(const float4*)(wb + j);
        float4 w1 = *(const float4*)(wb + j + 4);

        float p0 = a0.x * w0.x, p1 = a0.y * w0.y, p2 = a0.z * w0.z, p3 = a0.w * w0.w;
        float p4 = a1.x * w1.x, p5 = a1.y * w1.y, p6 = a1.z * w1.z, p7 = a1.w * w1.w;
        dsum += ((p0 + p1) + (p2 + p3)) + ((p4 + p5) + (p6 + p7));
        f16x8 af;
        af[0] = (_Float16)p0; af[1] = (_Float16)p1; af[2] = (_Float16)p2; af[3] = (_Float16)p3;
        af[4] = (_Float16)p4; af[5] = (_Float16)p5; af[6] = (_Float16)p6; af[7] = (_Float16)p7;
#pragma unroll
        for (int tt = 0; tt < 8; ++tt)
            acc[tt] = __builtin_amdgcn_mfma_f32_16x16x32_f16(af, bfv[tt], acc[tt], 0, 0, 0);
    }

    // denom: reduce across quads (lanes sharing m)
    dsum += __shfl_xor(dsum, 16, 64);
    dsum += __shfl_xor(dsum, 32, 64);

    if (kw > 0) {                        // K-parts 1..3 dump partials
        if (l < 16) dred[kw - 1][row_l] = dsum;
#pragma unroll
        for (int tt = 0; tt < 8; ++tt)
#pragma unroll
            for (int r = 0; r < 4; ++r)
                red[kw - 1][rw * 16 + q * 4 + r][tt * 16 + m] = acc[tt][r];
    }
    __syncthreads();
    if (kw == 0) {                       // K-part 0 combines + normalizes + stores
        float dtot = dsum + dred[0][row_l] + dred[1][row_l] + dred[2][row_l];
        float invd = 1.f / dtot;         // valid on lane for row m (any q)
        float* ob = out + (size_t)(b * Nn + i0 + rw * 16) * Cn;
#pragma unroll
        for (int r = 0; r < 4; ++r) {
            int rloc = q * 4 + r;        // C/D layout: row = q*4 + reg
            float iv = __shfl(invd, rloc, 64);
#pragma unroll
            for (int tt = 0; tt < 8; ++tt) {
                int cc = tt * 16 + m;
                float v = acc[tt][r] + red[0][rw * 16 + rloc][cc]
                                     + red[1][rw * 16 + rloc][cc]
                                     + red[2][rw * 16 + rloc][cc];
                ob[(size_t)rloc * Cn + cc] = v * iv;
            }
        }
    }
}

// ---------------------------------------------------------------------------
extern "C" void kernel_launch(void* const* d_in, const int* in_sizes, int n_in,
                              void* d_out, int out_size, void* d_ws, size_t ws_size,
                              hipStream_t stream) {
    const float* h  = (const float*)d_in[0];
    const float* A  = (const float*)d_in[1];
    const float* Ww = (const float*)d_in[2];
    const float* Wb = (const float*)d_in[3];
    const float* aw = (const float*)d_in[4];
    // d_in[5] = a_b : cancels in the row normalization, unused
    float* out = (float*)d_out;

    char* ws = (char*)d_ws;
    _Float16* hTt  = (_Float16*)ws;                                   // 8*64*128*32 f16 = 4 MB
    float*    wexp = (float*)(ws + (size_t)Bn * NKB * Cn * 32 * 2);   // 8*2048 f32 = 64 KB

    rows_kernel<<<Bn * (Nn / 64), 256, 0, stream>>>(h, Ww, Wb, aw, wexp, hTt);
    attn_kernel<<<Bn * (Nn / 32), 512, 0, stream>>>(A, wexp, hTt, out);
}